// Round 9
// baseline (574.357 us; speedup 1.0000x reference)
//
#include <hip/hip_runtime.h>
#include <hip/hip_bf16.h>

typedef __attribute__((ext_vector_type(8))) short bf16x8;   // 8 bf16 in 4 VGPRs
typedef __attribute__((ext_vector_type(4))) float f32x4;    // MFMA accumulator
typedef __attribute__((ext_vector_type(4))) int   i32x4;

#define NB 256
#define NT 200
#define NW 200
#define NE 768
#define NH 256
#define NEMB 32
#define KIN 800           // E + EMB
#define G3H 768           // 3*H
#define MROWS 51200       // B*T

__device__ __forceinline__ float bf2f(unsigned short h) {
    return __uint_as_float(((unsigned)h) << 16);
}
__device__ __forceinline__ unsigned short f2bf(float f) {
    unsigned u = __float_as_uint(f);
    u += 0x7fff + ((u >> 16) & 1);   // RNE
    return (unsigned short)(u >> 16);
}
__device__ __forceinline__ float sigm(float x) { return 1.0f / (1.0f + __expf(-x)); }
__device__ __forceinline__ float tanh_fast(float x) {
    float e = __expf(2.0f * x);
    return 1.0f - 2.0f / (e + 1.0f);
}

#if __has_builtin(__builtin_amdgcn_sdot4)
__device__ __forceinline__ int SDOT4(int a, int b, int c) {
    return __builtin_amdgcn_sdot4(a, b, c, false);
}
#else
__device__ __forceinline__ int SDOT4(int a, int b, int c) {   // exact fallback
    #pragma unroll
    for (int j = 0; j < 4; j++)
        c += (int)(signed char)(a >> (8 * j)) * (int)(signed char)(b >> (8 * j));
    return c;
}
#endif

// async global->LDS, 16 B/lane. LDS dest: wave-uniform base + lane*16.
__device__ __forceinline__ void gload16(const void* g, void* l) {
    __builtin_amdgcn_global_load_lds((const __attribute__((address_space(1))) unsigned int*)g,
                                     (__attribute__((address_space(3))) unsigned int*)l,
                                     16, 0, 0);
}

// ---------------------------------------------------------------------------
// prep1: A_bf16[51200][800] = [bf16(inputs) | bf16(emb_table[fix])],
//        W_ih -> bf16 [768][800], W_out -> bf16 [768][256],
//        biasC[768] = b_ih + (row<512 ? b_hh : 0)   (b_hh r,z folded into xg)
// ---------------------------------------------------------------------------
__global__ void prep1(const float* __restrict__ inputs, const int* __restrict__ fix_seq,
                      const float* __restrict__ emb, const float* __restrict__ Wih,
                      const float* __restrict__ Wout, const float* __restrict__ bih,
                      const float* __restrict__ bhh,
                      unsigned short* __restrict__ Abf, unsigned short* __restrict__ Wihbf,
                      unsigned short* __restrict__ Woutbf, float* __restrict__ biasC) {
    const long gid0 = (long)blockIdx.x * blockDim.x + threadIdx.x;
    if (gid0 < G3H) biasC[gid0] = bih[gid0] + (gid0 < 512 ? bhh[gid0] : 0.0f);
    const long NA = (long)MROWS * 100;   // 8 cols per unit
    const long NWU = 768L * 100;
    const long NOU = 768L * 32;
    const long total = NA + NWU + NOU;
    for (long u = gid0; u < total; u += (long)gridDim.x * blockDim.x) {
        bf16x8 v;
        unsigned short* dst;
        if (u < NA) {
            long row = u / 100;
            int c8 = (int)(u % 100) * 8;
            const float* s;
            if (c8 < NE) {
                s = inputs + row * NE + c8;
            } else {
                int fx = fix_seq[row];
                s = emb + (long)fx * NEMB + (c8 - NE);
            }
            #pragma unroll
            for (int j = 0; j < 8; j++) v[j] = (short)f2bf(s[j]);
            dst = Abf + row * KIN + c8;
        } else if (u < NA + NWU) {
            long u2 = u - NA;
            long row = u2 / 100;
            int c8 = (int)(u2 % 100) * 8;
            const float* s = Wih + row * KIN + c8;
            #pragma unroll
            for (int j = 0; j < 8; j++) v[j] = (short)f2bf(s[j]);
            dst = Wihbf + row * KIN + c8;
        } else {
            long u3 = u - NA - NWU;
            long row = u3 / 32;
            int c8 = (int)(u3 % 32) * 8;
            const float* s = Wout + row * NH + c8;
            #pragma unroll
            for (int j = 0; j < 8; j++) v[j] = (short)f2bf(s[j]);
            dst = Woutbf + row * NH + c8;
        }
        *(bf16x8*)dst = v;
    }
}

// ---------------------------------------------------------------------------
// gemm_bt128: Out[M][N] (bf16) = A[M][K](bf16) * Bw[N][K](bf16)^T + bias
// BM=BN=128, BK=32, 256 threads (4 waves, each 64x64).
// m97 pattern: global_load_lds width=16 staging; XCD-bijective swizzle.
// ---------------------------------------------------------------------------
__global__ __launch_bounds__(256)
void gemm_bt128(const unsigned short* __restrict__ A,
                const unsigned short* __restrict__ Bw,
                const float* __restrict__ bias,
                unsigned short* __restrict__ Out,
                int M, int N, int K) {
    __shared__ unsigned short As[128 * 32];
    __shared__ unsigned short Bs[128 * 32];
    const int bid = (int)((blockIdx.x & 7) * (gridDim.x >> 3) + (blockIdx.x >> 3));
    const int nblk = N >> 7;
    const int m0 = (bid / nblk) << 7;
    const int n0 = (bid % nblk) << 7;
    const int tid = threadIdx.x;
    const int lane = tid & 63;
    const int wave = tid >> 6;
    const int wm = (wave >> 1) << 6;
    const int wn = (wave & 1) << 6;
    const int nk = K >> 5;

    // staging: thread tid -> tile row tid>>2 (0..63), 16-B segment tid&3
    const int srow = tid >> 2;
    const int sseg = (tid & 3) << 4;
    const char* gA0 = (const char*)(A + (long)(m0 + srow) * K) + sseg;        // rows 0-63
    const char* gA1 = (const char*)(A + (long)(m0 + 64 + srow) * K) + sseg;   // rows 64-127
    const char* gB0 = (const char*)(Bw + (long)(n0 + srow) * K) + sseg;
    const char* gB1 = (const char*)(Bw + (long)(n0 + 64 + srow) * K) + sseg;
    char* lA0 = (char*)As + wave * 1024;           // bytes [0,4096) = rows 0-63
    char* lA1 = (char*)As + 4096 + wave * 1024;    // rows 64-127
    char* lB0 = (char*)Bs + wave * 1024;
    char* lB1 = (char*)Bs + 4096 + wave * 1024;

    f32x4 acc[4][4] = {};

    for (int kt = 0; kt < nk; kt++) {
        __syncthreads();                 // previous tile's reads complete
        gload16(gA0 + kt * 64, lA0);
        gload16(gA1 + kt * 64, lA1);
        gload16(gB0 + kt * 64, lB0);
        gload16(gB1 + kt * 64, lB1);
        asm volatile("s_waitcnt vmcnt(0)" ::: "memory");
        __syncthreads();                 // all waves' stages visible
        bf16x8 af[4], bfr[4];
        #pragma unroll
        for (int mi = 0; mi < 4; mi++)
            af[mi] = *(const bf16x8*)((const char*)As +
                        (wm + mi * 16 + (lane & 15)) * 64 + ((lane >> 4) << 4));
        #pragma unroll
        for (int ni = 0; ni < 4; ni++)
            bfr[ni] = *(const bf16x8*)((const char*)Bs +
                        (wn + ni * 16 + (lane & 15)) * 64 + ((lane >> 4) << 4));
        #pragma unroll
        for (int mi = 0; mi < 4; mi++)
            #pragma unroll
            for (int ni = 0; ni < 4; ni++)
                acc[mi][ni] = __builtin_amdgcn_mfma_f32_16x16x32_bf16(
                                  af[mi], bfr[ni], acc[mi][ni], 0, 0, 0);
    }
    // epilogue: D col = lane&15, row = (lane>>4)*4 + r  (m89-verified layout)
    #pragma unroll
    for (int ni = 0; ni < 4; ni++) {
        const int col = n0 + wn + ni * 16 + (lane & 15);
        const float bv = bias[col];
        #pragma unroll
        for (int mi = 0; mi < 4; mi++) {
            const int row = m0 + wm + mi * 16 + ((lane >> 4) << 2);
            #pragma unroll
            for (int r = 0; r < 4; r++)
                Out[(long)(row + r) * N + col] = f2bf(acc[mi][ni][r] + bv);
        }
    }
}

// ---------------------------------------------------------------------------
// gru_scan (fused): grid 512 x 512 threads, 2 blocks/CU co-resident
// (VGPR=128 each -> 4 waves/SIMD exactly fills the register file).
//   blocks [0,256):   int8 dot4 recurrence (R7 structure, unchanged)
//   blocks [256,512): prep2 streaming role (fwe fp32 -> bf16 + word_mask) —
//                     independent of the recurrence; its memory traffic
//                     executes in the gru blocks' stall cycles (47% idle).
// prep2 role writes fwebf into R0 (A region, dead after gemm1).
// ---------------------------------------------------------------------------
__global__ __launch_bounds__(512, 2)
__attribute__((amdgpu_waves_per_eu(2, 2)))
void gru_scan(const unsigned short* __restrict__ xg,   // [51200][768] bf16 (incl biasC)
              const float* __restrict__ Whh,            // [768][256] fp32
              const float* __restrict__ bhh,            // [768]
              const int* __restrict__ lengths,          // [256]
              unsigned short* __restrict__ hout,        // [51200][256] bf16 (masked)
              const float* __restrict__ fwe,            // [256][200][768] fp32
              unsigned short* __restrict__ fwebf,       // [51200][768] bf16 (R0)
              unsigned char* __restrict__ wmask) {      // [51200]
    __shared__ __align__(16) unsigned char h8[2][256];  // int8 h double buffer
    const int tid = threadIdx.x;
    const int lane = tid & 63;
    const int wave = tid >> 6;               // 0..7

    if (blockIdx.x >= NB) {
        // ---- prep2 role: pure streaming, no barriers, returns early ----
        const int blk = (int)blockIdx.x - NB;          // 0..255
        for (int row = blk * 8 + wave; row < MROWS; row += 2048) {
            const float* s = fwe + (long)row * NE;
            unsigned short* d = fwebf + (long)row * NE;
            float asum = 0.0f;
            #pragma unroll
            for (int i = 0; i < 12; i++) {
                const float v = s[lane + i * 64];
                asum += fabsf(v);
                d[lane + i * 64] = f2bf(v);
            }
            #pragma unroll
            for (int off = 32; off >= 1; off >>= 1) asum += __shfl_xor(asum, off);
            if (lane == 0) wmask[row] = (asum != 0.0f) ? 1 : 0;
        }
        return;
    }

    // ---- recurrence role (R7 structure, unchanged) ----
    const int b = blockIdx.x;
    const int col = wave * 32 + (lane & 31); // this thread's h-col
    const int kh = lane >> 5;                // K-half 0/1

    int W[3][32];
    #pragma unroll
    for (int g = 0; g < 3; g++) {
        const float* wr = Whh + (long)(g * 256 + col) * NH + kh * 128;
        #pragma unroll
        for (int d = 0; d < 32; d++) {
            const float4 f = *(const float4*)(wr + d * 4);
            unsigned pack = 0;
            #pragma unroll
            for (int j = 0; j < 4; j++) {
                const float fv = j == 0 ? f.x : j == 1 ? f.y : j == 2 ? f.z : f.w;
                int wq = (int)rintf(fv * 400.0f);
                wq = wq > 127 ? 127 : (wq < -127 ? -127 : wq);
                pack |= ((unsigned)(wq & 0xff)) << (8 * j);
            }
            W[g][d] = (int)pack;
        }
    }
    const float bhn = bhh[512 + col];        // n-gate b_hh (r,z folded into xg)
    const int len = lengths[b];
    if (tid < 128) ((unsigned*)h8)[tid] = 0u;   // zero both h buffers (512 B)

    const unsigned short* xrow = xg + (long)b * NT * G3H;
    unsigned short xv0 = xrow[col], xv1 = xrow[256 + col], xv2 = xrow[512 + col];
    float hp = 0.0f;
    const float ISC = 1.0f / (400.0f * 127.0f);
    const bool wlo = (lane < 32);

    asm volatile("s_waitcnt lgkmcnt(0)" ::: "memory");
    __builtin_amdgcn_sched_barrier(0);
    __builtin_amdgcn_s_barrier();
    __builtin_amdgcn_sched_barrier(0);

    for (int t = 0; t < NT; t++) {
        const unsigned char* hb = h8[(t + 1) & 1] + kh * 128;
        int p0a = 0, p0b = 0, p1a = 0, p1b = 0, p2a = 0, p2b = 0;
        #pragma unroll
        for (int r = 0; r < 8; r++) {
            const i32x4 hv = *(const i32x4*)(hb + r * 16);
            p0a = SDOT4(hv[0], W[0][r * 4 + 0], p0a);
            p1a = SDOT4(hv[0], W[1][r * 4 + 0], p1a);
            p2a = SDOT4(hv[0], W[2][r * 4 + 0], p2a);
            p0b = SDOT4(hv[1], W[0][r * 4 + 1], p0b);
            p1b = SDOT4(hv[1], W[1][r * 4 + 1], p1b);
            p2b = SDOT4(hv[1], W[2][r * 4 + 1], p2b);
            p0a = SDOT4(hv[2], W[0][r * 4 + 2], p0a);
            p1a = SDOT4(hv[2], W[1][r * 4 + 2], p1a);
            p2a = SDOT4(hv[2], W[2][r * 4 + 2], p2a);
            p0b = SDOT4(hv[3], W[0][r * 4 + 3], p0b);
            p1b = SDOT4(hv[3], W[1][r * 4 + 3], p1b);
            p2b = SDOT4(hv[3], W[2][r * 4 + 3], p2b);
        }
        int p0 = p0a + p0b, p1 = p1a + p1b, p2 = p2a + p2b;
        p0 += __shfl_xor(p0, 32);            // combine K-halves
        p1 += __shfl_xor(p1, 32);
        p2 += __shfl_xor(p2, 32);
        const float r = sigm(bf2f(xv0) + (float)p0 * ISC);
        const float z = sigm(bf2f(xv1) + (float)p1 * ISC);
        const float n = tanh_fast(bf2f(xv2) + r * ((float)p2 * ISC + bhn));
        hp = (1.0f - z) * n + z * hp;
        if (wlo) {
            h8[t & 1][col] = (unsigned char)((int)rintf(hp * 127.0f) & 0xff);
            hout[((long)b * NT + t) * NH + col] = (t < len) ? f2bf(hp) : (unsigned short)0;
        }
        if (t + 1 < NT) {
            const unsigned short* xn = xrow + (long)(t + 1) * G3H;
            xv0 = xn[col]; xv1 = xn[256 + col]; xv2 = xn[512 + col];
        }
        asm volatile("s_waitcnt lgkmcnt(0)" ::: "memory");
        __builtin_amdgcn_sched_barrier(0);
        __builtin_amdgcn_s_barrier();
        __builtin_amdgcn_sched_barrier(0);
    }
}

// ---------------------------------------------------------------------------
// logits_gemm: per-batch GEMM [200 x 768] x [200 x 768]^T with mask epilogue.
// ---------------------------------------------------------------------------
__global__ void logits_gemm(const unsigned short* __restrict__ Aproj,  // [51200][768]
                            const unsigned short* __restrict__ Bfwe,   // [51200][768]
                            const int* __restrict__ fix_seq,           // [256][200]
                            const unsigned char* __restrict__ wmask,   // [51200]
                            float* __restrict__ out) {
    __shared__ unsigned short As[64 * 32];
    __shared__ unsigned short Bs[64 * 32];
    const int blk = blockIdx.x;
    const int b = blk >> 4;
    const int mt = (blk >> 2) & 3;
    const int ntile = blk & 3;
    const int t0 = mt << 6;
    const int w0 = ntile << 6;
    const int tid = threadIdx.x;
    const int lane = tid & 63;
    const int wave = tid >> 6;
    const int wm = (wave >> 1) << 5;
    const int wn = (wave & 1) << 5;

    const int srow = tid >> 2;
    const int sbyte = (tid & 3) << 4;
    const int tA = t0 + srow > 199 ? 199 : t0 + srow;   // clamp OOB rows (masked later)
    const int wB = w0 + srow > 199 ? 199 : w0 + srow;
    const char* ga = (const char*)(Aproj + ((long)b * NT + tA) * NE) + sbyte;
    const char* gb = (const char*)(Bfwe + ((long)b * NW + wB) * NE) + sbyte;
    char* la = (char*)As + srow * 64 + sbyte;
    char* lb = (char*)Bs + srow * 64 + sbyte;

    f32x4 acc[2][2] = {};
    bf16x8 ra = *(const bf16x8*)(ga);
    bf16x8 rb = *(const bf16x8*)(gb);
    for (int kt = 0; kt < 24; kt++) {
        __syncthreads();
        *(bf16x8*)(la) = ra;
        *(bf16x8*)(lb) = rb;
        __syncthreads();
        if (kt < 23) {
            ra = *(const bf16x8*)(ga + (kt + 1) * 64);
            rb = *(const bf16x8*)(gb + (kt + 1) * 64);
        }
        bf16x8 af[2], bfr[2];
        #pragma unroll
        for (int mi = 0; mi < 2; mi++)
            af[mi] = *(const bf16x8*)((const char*)As +
                        (wm + mi * 16 + (lane & 15)) * 64 + ((lane >> 4) << 4));
        #pragma unroll
        for (int ni = 0; ni < 2; ni++)
            bfr[ni] = *(const bf16x8*)((const char*)Bs +
                        (wn + ni * 16 + (lane & 15)) * 64 + ((lane >> 4) << 4));
        #pragma unroll
        for (int mi = 0; mi < 2; mi++)
            #pragma unroll
            for (int ni = 0; ni < 2; ni++)
                acc[mi][ni] = __builtin_amdgcn_mfma_f32_16x16x32_bf16(
                                  af[mi], bfr[ni], acc[mi][ni], 0, 0, 0);
    }
    // epilogue with saccade-window + valid + word masks
    #pragma unroll
    for (int mi = 0; mi < 2; mi++) {
        #pragma unroll
        for (int r = 0; r < 4; r++) {
            const int t = t0 + wm + mi * 16 + ((lane >> 4) << 2) + r;
            if (t >= NT) continue;
            const int fx = fix_seq[b * NT + t];
            #pragma unroll
            for (int ni = 0; ni < 2; ni++) {
                const int w = w0 + wn + ni * 16 + (lane & 15);
                if (w >= NW) continue;
                int d = w - fx; d = d < 0 ? -d : d;
                const bool ok = (fx != 0) && (d <= 8) && (wmask[b * NW + w] != 0);
                out[(long)b * (NT * NW) + t * NW + w] = ok ? acc[mi][ni][r] : -1e9f;
            }
        }
    }
}

// ---------------------------------------------------------------------------
// dur_kernel: dur[b,t] = dot(hout[b,t,:], W_dur) + b_dur. One wave per row.
// ---------------------------------------------------------------------------
__global__ void dur_kernel(const unsigned short* __restrict__ hout,
                           const float* __restrict__ Wdur, const float* __restrict__ bdur,
                           float* __restrict__ out) {
    const int row = (int)((blockIdx.x * blockDim.x + threadIdx.x) >> 6);
    const int lane = threadIdx.x & 63;
    if (row >= MROWS) return;
    const unsigned short* hp = hout + (long)row * NH + lane * 4;
    const uint2 hv = *(const uint2*)hp;
    const float4 wv = *(const float4*)(Wdur + lane * 4);
    float s = bf2f((unsigned short)(hv.x & 0xffff)) * wv.x
            + bf2f((unsigned short)(hv.x >> 16)) * wv.y
            + bf2f((unsigned short)(hv.y & 0xffff)) * wv.z
            + bf2f((unsigned short)(hv.y >> 16)) * wv.w;
    #pragma unroll
    for (int off = 32; off >= 1; off >>= 1) s += __shfl_down(s, off);
    if (lane == 0) out[(long)NB * NT * NW + row] = s + bdur[0];
}

// ---------------------------------------------------------------------------
extern "C" void kernel_launch(void* const* d_in, const int* in_sizes, int n_in,
                              void* d_out, int out_size, void* d_ws, size_t ws_size,
                              hipStream_t stream) {
    (void)in_sizes; (void)n_in; (void)out_size; (void)ws_size;
    const float* inputs  = (const float*)d_in[0];
    const int*   fix_seq = (const int*)d_in[1];
    const float* fwe     = (const float*)d_in[2];
    const int*   lengths = (const int*)d_in[3];
    const float* emb     = (const float*)d_in[5];
    const float* Wih     = (const float*)d_in[6];
    const float* bih     = (const float*)d_in[7];
    const float* Whh     = (const float*)d_in[8];
    const float* bhh     = (const float*)d_in[9];
    const float* Wout    = (const float*)d_in[10];
    const float* bout    = (const float*)d_in[11];
    const float* Wdur    = (const float*)d_in[12];
    const float* bdur    = (const float*)d_in[13];
    float* out = (float*)d_out;

    char* ws = (char*)d_ws;
    // region layout (bytes, all 256-aligned):
    //   R0 [0, 81,920,000)            A_bf16 [51200][800]  -> fwebf after gemm1
    //   R1 [81,920,000, +78,643,200)  xg_bf16 [51200][768] -> proj after gru
    //   R2 [160,563,200, +26,214,400) hout_bf16 [51200][256]
    //   [186,777,600, +1,228,800)     W_ih bf16
    //   [188,006,400, +393,216)       W_out bf16
    //   [188,399,616, +51,200)        word_mask u8
    //   [188,450,816, +3,072)         biasC f32 [768]
    unsigned short* Abf    = (unsigned short*)(ws);
    unsigned short* xgbf   = (unsigned short*)(ws + 81920000);
    unsigned short* hout   = (unsigned short*)(ws + 160563200);
    unsigned short* Wihbf  = (unsigned short*)(ws + 186777600);
    unsigned short* Woutbf = (unsigned short*)(ws + 188006400);
    unsigned char*  wmask  = (unsigned char*)(ws + 188399616);
    float*          biasC  = (float*)(ws + 188450816);
    unsigned short* fwebf  = Abf;    // R0: A dead after gemm1 (gru reads only xg)
    unsigned short* projbf = xgbf;   // R1: xg dead after gru

    prep1<<<2048, 256, 0, stream>>>(inputs, fix_seq, emb, Wih, Wout, bih, bhh,
                                    Abf, Wihbf, Woutbf, biasC);
    gemm_bt128<<<400 * 6, 256, 0, stream>>>(Abf, Wihbf, biasC, xgbf, MROWS, G3H, KIN);
    gru_scan<<<512, 512, 0, stream>>>(xgbf, Whh, bhh, lengths, hout, fwe, fwebf, wmask);
    gemm_bt128<<<400 * 6, 256, 0, stream>>>(hout, Woutbf, bout, projbf, MROWS, G3H, NH);
    logits_gemm<<<4096, 256, 0, stream>>>(projbf, fwebf, fix_seq, wmask, out);
    dur_kernel<<<12800, 256, 0, stream>>>(hout, Wdur, bdur, out);
}

// Round 10
// 522.070 us; speedup vs baseline: 1.1002x; 1.1002x over previous
//
#include <hip/hip_runtime.h>
#include <hip/hip_bf16.h>

typedef __attribute__((ext_vector_type(8))) short bf16x8;   // 8 bf16 in 4 VGPRs
typedef __attribute__((ext_vector_type(4))) float f32x4;    // MFMA accumulator
typedef __attribute__((ext_vector_type(4))) int   i32x4;

#define NB 256
#define NT 200
#define NW 200
#define NE 768
#define NH 256
#define NEMB 32
#define KIN 800           // E + EMB
#define G3H 768           // 3*H
#define MROWS 51200       // B*T

__device__ __forceinline__ float bf2f(unsigned short h) {
    return __uint_as_float(((unsigned)h) << 16);
}
__device__ __forceinline__ unsigned short f2bf(float f) {
    unsigned u = __float_as_uint(f);
    u += 0x7fff + ((u >> 16) & 1);   // RNE
    return (unsigned short)(u >> 16);
}
__device__ __forceinline__ float sigm(float x) { return 1.0f / (1.0f + __expf(-x)); }
__device__ __forceinline__ float tanh_fast(float x) {
    float e = __expf(2.0f * x);
    return 1.0f - 2.0f / (e + 1.0f);
}

#if __has_builtin(__builtin_amdgcn_sdot4)
__device__ __forceinline__ int SDOT4(int a, int b, int c) {
    return __builtin_amdgcn_sdot4(a, b, c, false);
}
#else
__device__ __forceinline__ int SDOT4(int a, int b, int c) {   // exact fallback
    #pragma unroll
    for (int j = 0; j < 4; j++)
        c += (int)(signed char)(a >> (8 * j)) * (int)(signed char)(b >> (8 * j));
    return c;
}
#endif

// async global->LDS, 16 B/lane. LDS dest: wave-uniform base + lane*16.
__device__ __forceinline__ void gload16(const void* g, void* l) {
    __builtin_amdgcn_global_load_lds((const __attribute__((address_space(1))) unsigned int*)g,
                                     (__attribute__((address_space(3))) unsigned int*)l,
                                     16, 0, 0);
}

// ---------------------------------------------------------------------------
// prep1: A_bf16[51200][800] = [bf16(inputs) | bf16(emb_table[fix])],
//        W_ih -> bf16 [768][800], W_out -> bf16 TRANSPOSED [256][768],
//        biasC[768] = b_ih + (row<512 ? b_hh : 0), bias0[256] = 0
// ---------------------------------------------------------------------------
__global__ void prep1(const float* __restrict__ inputs, const int* __restrict__ fix_seq,
                      const float* __restrict__ emb, const float* __restrict__ Wih,
                      const float* __restrict__ Wout, const float* __restrict__ bih,
                      const float* __restrict__ bhh,
                      unsigned short* __restrict__ Abf, unsigned short* __restrict__ Wihbf,
                      unsigned short* __restrict__ WoutTbf, float* __restrict__ biasC,
                      float* __restrict__ bias0) {
    const long gid0 = (long)blockIdx.x * blockDim.x + threadIdx.x;
    if (gid0 < G3H) biasC[gid0] = bih[gid0] + (gid0 < 512 ? bhh[gid0] : 0.0f);
    if (gid0 < NH) bias0[gid0] = 0.0f;
    const long NA = (long)MROWS * 100;   // 8 cols per unit
    const long NWU = 768L * 100;
    const long NOU = 256L * 96;          // WoutT: 256 rows x 96 8-col chunks
    const long total = NA + NWU + NOU;
    for (long u = gid0; u < total; u += (long)gridDim.x * blockDim.x) {
        bf16x8 v;
        unsigned short* dst;
        if (u < NA) {
            long row = u / 100;
            int c8 = (int)(u % 100) * 8;
            const float* s;
            if (c8 < NE) {
                s = inputs + row * NE + c8;
            } else {
                int fx = fix_seq[row];
                s = emb + (long)fx * NEMB + (c8 - NE);
            }
            #pragma unroll
            for (int j = 0; j < 8; j++) v[j] = (short)f2bf(s[j]);
            dst = Abf + row * KIN + c8;
        } else if (u < NA + NWU) {
            long u2 = u - NA;
            long row = u2 / 100;
            int c8 = (int)(u2 % 100) * 8;
            const float* s = Wih + row * KIN + c8;
            #pragma unroll
            for (int j = 0; j < 8; j++) v[j] = (short)f2bf(s[j]);
            dst = Wihbf + row * KIN + c8;
        } else {
            long u3 = u - NA - NWU;
            long row = u3 / 96;          // h index 0..255
            int c8 = (int)(u3 % 96) * 8; // e chunk
            #pragma unroll
            for (int j = 0; j < 8; j++)
                v[j] = (short)f2bf(Wout[(long)(c8 + j) * NH + row]);   // transpose gather
            dst = WoutTbf + row * NE + c8;
        }
        *(bf16x8*)dst = v;
    }
}

// ---------------------------------------------------------------------------
// gemm_bt128: Out[M][N] (bf16) = A[M][K](bf16) * Bw[N][K](bf16)^T + bias
// BM=BN=128, BK=32, 256 threads (4 waves, each 64x64).
// m97 pattern: global_load_lds width=16 staging; XCD-bijective swizzle.
// ---------------------------------------------------------------------------
__global__ __launch_bounds__(256)
void gemm_bt128(const unsigned short* __restrict__ A,
                const unsigned short* __restrict__ Bw,
                const float* __restrict__ bias,
                unsigned short* __restrict__ Out,
                int M, int N, int K) {
    __shared__ unsigned short As[128 * 32];
    __shared__ unsigned short Bs[128 * 32];
    const int bid = (int)((blockIdx.x & 7) * (gridDim.x >> 3) + (blockIdx.x >> 3));
    const int nblk = N >> 7;
    const int m0 = (bid / nblk) << 7;
    const int n0 = (bid % nblk) << 7;
    const int tid = threadIdx.x;
    const int lane = tid & 63;
    const int wave = tid >> 6;
    const int wm = (wave >> 1) << 6;
    const int wn = (wave & 1) << 6;
    const int nk = K >> 5;

    // staging: thread tid -> tile row tid>>2 (0..63), 16-B segment tid&3
    const int srow = tid >> 2;
    const int sseg = (tid & 3) << 4;
    const char* gA0 = (const char*)(A + (long)(m0 + srow) * K) + sseg;        // rows 0-63
    const char* gA1 = (const char*)(A + (long)(m0 + 64 + srow) * K) + sseg;   // rows 64-127
    const char* gB0 = (const char*)(Bw + (long)(n0 + srow) * K) + sseg;
    const char* gB1 = (const char*)(Bw + (long)(n0 + 64 + srow) * K) + sseg;
    char* lA0 = (char*)As + wave * 1024;           // bytes [0,4096) = rows 0-63
    char* lA1 = (char*)As + 4096 + wave * 1024;    // rows 64-127
    char* lB0 = (char*)Bs + wave * 1024;
    char* lB1 = (char*)Bs + 4096 + wave * 1024;

    f32x4 acc[4][4] = {};

    for (int kt = 0; kt < nk; kt++) {
        __syncthreads();                 // previous tile's reads complete
        gload16(gA0 + kt * 64, lA0);
        gload16(gA1 + kt * 64, lA1);
        gload16(gB0 + kt * 64, lB0);
        gload16(gB1 + kt * 64, lB1);
        asm volatile("s_waitcnt vmcnt(0)" ::: "memory");
        __syncthreads();                 // all waves' stages visible
        bf16x8 af[4], bfr[4];
        #pragma unroll
        for (int mi = 0; mi < 4; mi++)
            af[mi] = *(const bf16x8*)((const char*)As +
                        (wm + mi * 16 + (lane & 15)) * 64 + ((lane >> 4) << 4));
        #pragma unroll
        for (int ni = 0; ni < 4; ni++)
            bfr[ni] = *(const bf16x8*)((const char*)Bs +
                        (wn + ni * 16 + (lane & 15)) * 64 + ((lane >> 4) << 4));
        #pragma unroll
        for (int mi = 0; mi < 4; mi++)
            #pragma unroll
            for (int ni = 0; ni < 4; ni++)
                acc[mi][ni] = __builtin_amdgcn_mfma_f32_16x16x32_bf16(
                                  af[mi], bfr[ni], acc[mi][ni], 0, 0, 0);
    }
    // epilogue: D col = lane&15, row = (lane>>4)*4 + r  (m89-verified layout)
    #pragma unroll
    for (int ni = 0; ni < 4; ni++) {
        const int col = n0 + wn + ni * 16 + (lane & 15);
        const float bv = bias[col];
        #pragma unroll
        for (int mi = 0; mi < 4; mi++) {
            const int row = m0 + wm + mi * 16 + ((lane >> 4) << 2);
            #pragma unroll
            for (int r = 0; r < 4; r++)
                Out[(long)(row + r) * N + col] = f2bf(acc[mi][ni][r] + bv);
        }
    }
}

// ---------------------------------------------------------------------------
// gru_scan: 256 blocks (1 batch each), 512 threads (8 waves, 2/SIMD).
// Pure-VALU int8 GEMV via v_dot4_i32_i8 (R7/R8 structure, unchanged).
// ---------------------------------------------------------------------------
__global__ __launch_bounds__(512, 2)
__attribute__((amdgpu_waves_per_eu(2, 2)))
void gru_scan(const unsigned short* __restrict__ xg,   // [51200][768] bf16 (incl biasC)
              const float* __restrict__ Whh,            // [768][256] fp32
              const float* __restrict__ bhh,            // [768]
              const int* __restrict__ lengths,          // [256]
              unsigned short* __restrict__ hout) {      // [51200][256] bf16 (masked)
    __shared__ __align__(16) unsigned char h8[2][256];  // int8 h double buffer
    const int tid = threadIdx.x;
    const int lane = tid & 63;
    const int wave = tid >> 6;               // 0..7
    const int b = blockIdx.x;
    const int col = wave * 32 + (lane & 31); // this thread's h-col
    const int kh = lane >> 5;                // K-half 0/1

    int W[3][32];
    #pragma unroll
    for (int g = 0; g < 3; g++) {
        const float* wr = Whh + (long)(g * 256 + col) * NH + kh * 128;
        #pragma unroll
        for (int d = 0; d < 32; d++) {
            const float4 f = *(const float4*)(wr + d * 4);
            unsigned pack = 0;
            #pragma unroll
            for (int j = 0; j < 4; j++) {
                const float fv = j == 0 ? f.x : j == 1 ? f.y : j == 2 ? f.z : f.w;
                int wq = (int)rintf(fv * 400.0f);
                wq = wq > 127 ? 127 : (wq < -127 ? -127 : wq);
                pack |= ((unsigned)(wq & 0xff)) << (8 * j);
            }
            W[g][d] = (int)pack;
        }
    }
    const float bhn = bhh[512 + col];        // n-gate b_hh (r,z folded into xg)
    const int len = lengths[b];
    if (tid < 128) ((unsigned*)h8)[tid] = 0u;   // zero both h buffers (512 B)

    const unsigned short* xrow = xg + (long)b * NT * G3H;
    unsigned short xv0 = xrow[col], xv1 = xrow[256 + col], xv2 = xrow[512 + col];
    float hp = 0.0f;
    const float ISC = 1.0f / (400.0f * 127.0f);
    const bool wlo = (lane < 32);

    asm volatile("s_waitcnt lgkmcnt(0)" ::: "memory");
    __builtin_amdgcn_sched_barrier(0);
    __builtin_amdgcn_s_barrier();
    __builtin_amdgcn_sched_barrier(0);

    for (int t = 0; t < NT; t++) {
        const unsigned char* hb = h8[(t + 1) & 1] + kh * 128;
        int p0a = 0, p0b = 0, p1a = 0, p1b = 0, p2a = 0, p2b = 0;
        #pragma unroll
        for (int r = 0; r < 8; r++) {
            const i32x4 hv = *(const i32x4*)(hb + r * 16);
            p0a = SDOT4(hv[0], W[0][r * 4 + 0], p0a);
            p1a = SDOT4(hv[0], W[1][r * 4 + 0], p1a);
            p2a = SDOT4(hv[0], W[2][r * 4 + 0], p2a);
            p0b = SDOT4(hv[1], W[0][r * 4 + 1], p0b);
            p1b = SDOT4(hv[1], W[1][r * 4 + 1], p1b);
            p2b = SDOT4(hv[1], W[2][r * 4 + 1], p2b);
            p0a = SDOT4(hv[2], W[0][r * 4 + 2], p0a);
            p1a = SDOT4(hv[2], W[1][r * 4 + 2], p1a);
            p2a = SDOT4(hv[2], W[2][r * 4 + 2], p2a);
            p0b = SDOT4(hv[3], W[0][r * 4 + 3], p0b);
            p1b = SDOT4(hv[3], W[1][r * 4 + 3], p1b);
            p2b = SDOT4(hv[3], W[2][r * 4 + 3], p2b);
        }
        int p0 = p0a + p0b, p1 = p1a + p1b, p2 = p2a + p2b;
        p0 += __shfl_xor(p0, 32);            // combine K-halves
        p1 += __shfl_xor(p1, 32);
        p2 += __shfl_xor(p2, 32);
        const float r = sigm(bf2f(xv0) + (float)p0 * ISC);
        const float z = sigm(bf2f(xv1) + (float)p1 * ISC);
        const float n = tanh_fast(bf2f(xv2) + r * ((float)p2 * ISC + bhn));
        hp = (1.0f - z) * n + z * hp;
        if (wlo) {
            h8[t & 1][col] = (unsigned char)((int)rintf(hp * 127.0f) & 0xff);
            hout[((long)b * NT + t) * NH + col] = (t < len) ? f2bf(hp) : (unsigned short)0;
        }
        if (t + 1 < NT) {
            const unsigned short* xn = xrow + (long)(t + 1) * G3H;
            xv0 = xn[col]; xv1 = xn[256 + col]; xv2 = xn[512 + col];
        }
        asm volatile("s_waitcnt lgkmcnt(0)" ::: "memory");
        __builtin_amdgcn_sched_barrier(0);
        __builtin_amdgcn_s_barrier();
        __builtin_amdgcn_sched_barrier(0);
    }
}

// ---------------------------------------------------------------------------
// prep2: fwe fp32 -> bf16, word_mask (sum|row| != 0), dvec[row] = fwe_row·b_out.
// One wave per row.
// ---------------------------------------------------------------------------
__global__ void prep2(const float* __restrict__ fwe, const float* __restrict__ bout,
                      unsigned short* __restrict__ fwebf,
                      unsigned char* __restrict__ wmask, float* __restrict__ dvec) {
    const int row = (int)((blockIdx.x * blockDim.x + threadIdx.x) >> 6);
    const int lane = threadIdx.x & 63;
    if (row >= MROWS) return;
    const float* s = fwe + (long)row * NE;
    unsigned short* d = fwebf + (long)row * NE;
    float asum = 0.0f, vdot = 0.0f;
    #pragma unroll
    for (int i = 0; i < 12; i++) {
        const float v = s[lane + i * 64];
        asum += fabsf(v);
        vdot += v * bout[lane + i * 64];
        d[lane + i * 64] = f2bf(v);
    }
    #pragma unroll
    for (int off = 32; off >= 1; off >>= 1) {
        asum += __shfl_xor(asum, off);
        vdot += __shfl_xor(vdot, off);
    }
    if (lane == 0) {
        wmask[row] = (asum != 0.0f) ? 1 : 0;
        dvec[row] = vdot;
    }
}

// ---------------------------------------------------------------------------
// logits_gemm: per-batch GEMM [200 x 256] x [200 x 256]^T (K=256 via the
// associativity rewrite: logits = hout @ (fwe @ W_out)^T + dvec) with mask
// epilogue. 64x64 tiles, 4 waves of 32x32; gload16 staging.
// ---------------------------------------------------------------------------
__global__ __launch_bounds__(256)
void logits_gemm(const unsigned short* __restrict__ Hrow,   // hout [51200][256]
                 const unsigned short* __restrict__ G,      // [51200][256]
                 const int* __restrict__ fix_seq,           // [256][200]
                 const unsigned char* __restrict__ wmask,   // [51200]
                 const float* __restrict__ dvec,            // [51200]
                 float* __restrict__ out) {
    __shared__ unsigned short As[64 * 32];
    __shared__ unsigned short Bs[64 * 32];
    const int blk = blockIdx.x;
    const int b = blk >> 4;
    const int mt = (blk >> 2) & 3;
    const int ntile = blk & 3;
    const int t0 = mt << 6;
    const int w0 = ntile << 6;
    const int tid = threadIdx.x;
    const int lane = tid & 63;
    const int wave = tid >> 6;
    const int wm = (wave >> 1) << 5;
    const int wn = (wave & 1) << 5;

    const int srow = tid >> 2;
    const int sseg = (tid & 3) << 4;
    const int tA = t0 + srow > 199 ? 199 : t0 + srow;   // clamp OOB rows (masked later)
    const int wB = w0 + srow > 199 ? 199 : w0 + srow;
    const char* ga = (const char*)(Hrow + ((long)b * NT + tA) * NH) + sseg;
    const char* gb = (const char*)(G + ((long)b * NW + wB) * NH) + sseg;
    char* la = (char*)As + wave * 1024;
    char* lb = (char*)Bs + wave * 1024;

    f32x4 acc[2][2] = {};
    for (int kt = 0; kt < 8; kt++) {     // K = 256
        __syncthreads();
        gload16(ga + kt * 64, la);
        gload16(gb + kt * 64, lb);
        asm volatile("s_waitcnt vmcnt(0)" ::: "memory");
        __syncthreads();
        bf16x8 af[2], bfr[2];
        #pragma unroll
        for (int mi = 0; mi < 2; mi++)
            af[mi] = *(const bf16x8*)((const char*)As +
                        (wm + mi * 16 + (lane & 15)) * 64 + ((lane >> 4) << 4));
        #pragma unroll
        for (int ni = 0; ni < 2; ni++)
            bfr[ni] = *(const bf16x8*)((const char*)Bs +
                        (wn + ni * 16 + (lane & 15)) * 64 + ((lane >> 4) << 4));
        #pragma unroll
        for (int mi = 0; mi < 2; mi++)
            #pragma unroll
            for (int ni = 0; ni < 2; ni++)
                acc[mi][ni] = __builtin_amdgcn_mfma_f32_16x16x32_bf16(
                                  af[mi], bfr[ni], acc[mi][ni], 0, 0, 0);
    }
    // epilogue with saccade-window + valid + word masks, + b_out·fwe term
    #pragma unroll
    for (int mi = 0; mi < 2; mi++) {
        #pragma unroll
        for (int r = 0; r < 4; r++) {
            const int t = t0 + wm + mi * 16 + ((lane >> 4) << 2) + r;
            if (t >= NT) continue;
            const int fx = fix_seq[b * NT + t];
            #pragma unroll
            for (int ni = 0; ni < 2; ni++) {
                const int w = w0 + wn + ni * 16 + (lane & 15);
                if (w >= NW) continue;
                int d = w - fx; d = d < 0 ? -d : d;
                const bool ok = (fx != 0) && (d <= 8) && (wmask[b * NW + w] != 0);
                out[(long)b * (NT * NW) + t * NW + w] =
                    ok ? acc[mi][ni][r] + dvec[b * NW + w] : -1e9f;
            }
        }
    }
}

// ---------------------------------------------------------------------------
// dur_kernel: dur[b,t] = dot(hout[b,t,:], W_dur) + b_dur. One wave per row.
// ---------------------------------------------------------------------------
__global__ void dur_kernel(const unsigned short* __restrict__ hout,
                           const float* __restrict__ Wdur, const float* __restrict__ bdur,
                           float* __restrict__ out) {
    const int row = (int)((blockIdx.x * blockDim.x + threadIdx.x) >> 6);
    const int lane = threadIdx.x & 63;
    if (row >= MROWS) return;
    const unsigned short* hp = hout + (long)row * NH + lane * 4;
    const uint2 hv = *(const uint2*)hp;
    const float4 wv = *(const float4*)(Wdur + lane * 4);
    float s = bf2f((unsigned short)(hv.x & 0xffff)) * wv.x
            + bf2f((unsigned short)(hv.x >> 16)) * wv.y
            + bf2f((unsigned short)(hv.y & 0xffff)) * wv.z
            + bf2f((unsigned short)(hv.y >> 16)) * wv.w;
    #pragma unroll
    for (int off = 32; off >= 1; off >>= 1) s += __shfl_down(s, off);
    if (lane == 0) out[(long)NB * NT * NW + row] = s + bdur[0];
}

// ---------------------------------------------------------------------------
extern "C" void kernel_launch(void* const* d_in, const int* in_sizes, int n_in,
                              void* d_out, int out_size, void* d_ws, size_t ws_size,
                              hipStream_t stream) {
    (void)in_sizes; (void)n_in; (void)out_size; (void)ws_size;
    const float* inputs  = (const float*)d_in[0];
    const int*   fix_seq = (const int*)d_in[1];
    const float* fwe     = (const float*)d_in[2];
    const int*   lengths = (const int*)d_in[3];
    const float* emb     = (const float*)d_in[5];
    const float* Wih     = (const float*)d_in[6];
    const float* bih     = (const float*)d_in[7];
    const float* Whh     = (const float*)d_in[8];
    const float* bhh     = (const float*)d_in[9];
    const float* Wout    = (const float*)d_in[10];
    const float* bout    = (const float*)d_in[11];
    const float* Wdur    = (const float*)d_in[12];
    const float* bdur    = (const float*)d_in[13];
    float* out = (float*)d_out;

    char* ws = (char*)d_ws;
    // region layout (bytes, all 256-aligned):
    //   R0 [0, 81,920,000)            A_bf16 [51200][800]  -> fwebf after gemm1
    //   R1 [81,920,000, +78,643,200)  xg_bf16 [51200][768] -> G [51200][256] after gru
    //   R2 [160,563,200, +26,214,400) hout_bf16 [51200][256]
    //   [186,777,600, +1,228,800)     W_ih bf16
    //   [188,006,400, +393,216)       W_outT bf16 [256][768]
    //   [188,399,616, +51,200)        word_mask u8
    //   [188,450,816, +3,072)         biasC f32 [768]
    //   [188,453,888, +204,800)       dvec f32 [51200]
    //   [188,658,688, +1,024)         bias0 f32 [256]
    unsigned short* Abf     = (unsigned short*)(ws);
    unsigned short* xgbf    = (unsigned short*)(ws + 81920000);
    unsigned short* hout    = (unsigned short*)(ws + 160563200);
    unsigned short* Wihbf   = (unsigned short*)(ws + 186777600);
    unsigned short* WoutTbf = (unsigned short*)(ws + 188006400);
    unsigned char*  wmask   = (unsigned char*)(ws + 188399616);
    float*          biasC   = (float*)(ws + 188450816);
    float*          dvec    = (float*)(ws + 188453888);
    float*          bias0   = (float*)(ws + 188658688);
    unsigned short* fwebf   = Abf;    // R0: A dead after gemm1
    unsigned short* Gbf     = xgbf;   // R1: xg dead after gru

    prep1<<<2048, 256, 0, stream>>>(inputs, fix_seq, emb, Wih, Wout, bih, bhh,
                                    Abf, Wihbf, WoutTbf, biasC, bias0);
    gemm_bt128<<<400 * 6, 256, 0, stream>>>(Abf, Wihbf, biasC, xgbf, MROWS, G3H, KIN);
    prep2<<<12800, 256, 0, stream>>>(fwe, bout, fwebf, wmask, dvec);
    gru_scan<<<256, 512, 0, stream>>>(xgbf, Whh, bhh, lengths, hout);
    gemm_bt128<<<400 * 2, 256, 0, stream>>>(fwebf, WoutTbf, bias0, Gbf, MROWS, NH, NE);
    logits_gemm<<<4096, 256, 0, stream>>>(hout, Gbf, fix_seq, wmask, dvec, out);
    dur_kernel<<<12800, 256, 0, stream>>>(hout, Wdur, bdur, out);
}

// Round 11
// 508.647 us; speedup vs baseline: 1.1292x; 1.0264x over previous
//
#include <hip/hip_runtime.h>
#include <hip/hip_bf16.h>

typedef __attribute__((ext_vector_type(8))) short bf16x8;   // 8 bf16 in 4 VGPRs
typedef __attribute__((ext_vector_type(4))) float f32x4;    // MFMA accumulator
typedef __attribute__((ext_vector_type(4))) int   i32x4;

#define NB 256
#define NT 200
#define NW 200
#define NE 768
#define NH 256
#define NEMB 32
#define KIN 800           // E + EMB
#define G3H 768           // 3*H
#define MROWS 51200       // B*T

__device__ __forceinline__ float bf2f(unsigned short h) {
    return __uint_as_float(((unsigned)h) << 16);
}
__device__ __forceinline__ unsigned short f2bf(float f) {
    unsigned u = __float_as_uint(f);
    u += 0x7fff + ((u >> 16) & 1);   // RNE
    return (unsigned short)(u >> 16);
}
__device__ __forceinline__ float sigm(float x) { return 1.0f / (1.0f + __expf(-x)); }
__device__ __forceinline__ float tanh_fast(float x) {
    float e = __expf(2.0f * x);
    return 1.0f - 2.0f / (e + 1.0f);
}

#if __has_builtin(__builtin_amdgcn_sdot4)
__device__ __forceinline__ int SDOT4(int a, int b, int c) {
    return __builtin_amdgcn_sdot4(a, b, c, false);
}
#else
__device__ __forceinline__ int SDOT4(int a, int b, int c) {   // exact fallback
    #pragma unroll
    for (int j = 0; j < 4; j++)
        c += (int)(signed char)(a >> (8 * j)) * (int)(signed char)(b >> (8 * j));
    return c;
}
#endif

// async global->LDS, 16 B/lane. LDS dest: wave-uniform base + lane*16.
__device__ __forceinline__ void gload16(const void* g, void* l) {
    __builtin_amdgcn_global_load_lds((const __attribute__((address_space(1))) unsigned int*)g,
                                     (__attribute__((address_space(3))) unsigned int*)l,
                                     16, 0, 0);
}

// ---------------------------------------------------------------------------
// prep1: A_bf16[51200][800] = [bf16(inputs) | bf16(emb_table[fix])],
//        W_ih -> bf16 [768][800], W_out -> bf16 TRANSPOSED [256][768],
//        biasC[768] = b_ih + (row<512 ? b_hh : 0), bias0[256] = 0
// ---------------------------------------------------------------------------
__global__ void prep1(const float* __restrict__ inputs, const int* __restrict__ fix_seq,
                      const float* __restrict__ emb, const float* __restrict__ Wih,
                      const float* __restrict__ Wout, const float* __restrict__ bih,
                      const float* __restrict__ bhh,
                      unsigned short* __restrict__ Abf, unsigned short* __restrict__ Wihbf,
                      unsigned short* __restrict__ WoutTbf, float* __restrict__ biasC,
                      float* __restrict__ bias0) {
    const long gid0 = (long)blockIdx.x * blockDim.x + threadIdx.x;
    if (gid0 < G3H) biasC[gid0] = bih[gid0] + (gid0 < 512 ? bhh[gid0] : 0.0f);
    if (gid0 < NH) bias0[gid0] = 0.0f;
    const long NA = (long)MROWS * 100;   // 8 cols per unit
    const long NWU = 768L * 100;
    const long NOU = 256L * 96;          // WoutT: 256 rows x 96 8-col chunks
    const long total = NA + NWU + NOU;
    for (long u = gid0; u < total; u += (long)gridDim.x * blockDim.x) {
        bf16x8 v;
        unsigned short* dst;
        if (u < NA) {
            long row = u / 100;
            int c8 = (int)(u % 100) * 8;
            const float* s;
            if (c8 < NE) {
                s = inputs + row * NE + c8;
            } else {
                int fx = fix_seq[row];
                s = emb + (long)fx * NEMB + (c8 - NE);
            }
            #pragma unroll
            for (int j = 0; j < 8; j++) v[j] = (short)f2bf(s[j]);
            dst = Abf + row * KIN + c8;
        } else if (u < NA + NWU) {
            long u2 = u - NA;
            long row = u2 / 100;
            int c8 = (int)(u2 % 100) * 8;
            const float* s = Wih + row * KIN + c8;
            #pragma unroll
            for (int j = 0; j < 8; j++) v[j] = (short)f2bf(s[j]);
            dst = Wihbf + row * KIN + c8;
        } else {
            long u3 = u - NA - NWU;
            long row = u3 / 96;          // h index 0..255
            int c8 = (int)(u3 % 96) * 8; // e chunk
            #pragma unroll
            for (int j = 0; j < 8; j++)
                v[j] = (short)f2bf(Wout[(long)(c8 + j) * NH + row]);   // transpose gather
            dst = WoutTbf + row * NE + c8;
        }
        *(bf16x8*)dst = v;
    }
}

// ---------------------------------------------------------------------------
// gemm_bt128: Out[M][N] (bf16) = A[M][K](bf16) * Bw[N][K](bf16)^T + bias
// BM=BN=128, BK=32, 256 threads (4 waves, each 64x64).
// T3 minimum 2-phase: double-buffered LDS; stage tile t+1 (gload16 async)
// BEFORE computing tile t; single __syncthreads()/iter (its implicit
// vmcnt(0)+lgkmcnt(0) drain is exactly the required wait). HBM latency of
// the stage hides under the 16 MFMAs. XCD-bijective blockIdx swizzle.
// ---------------------------------------------------------------------------
__global__ __launch_bounds__(256)
void gemm_bt128(const unsigned short* __restrict__ A,
                const unsigned short* __restrict__ Bw,
                const float* __restrict__ bias,
                unsigned short* __restrict__ Out,
                int M, int N, int K) {
    __shared__ unsigned short As[2][128 * 32];
    __shared__ unsigned short Bs[2][128 * 32];
    const int bid = (int)((blockIdx.x & 7) * (gridDim.x >> 3) + (blockIdx.x >> 3));
    const int nblk = N >> 7;
    const int m0 = (bid / nblk) << 7;
    const int n0 = (bid % nblk) << 7;
    const int tid = threadIdx.x;
    const int lane = tid & 63;
    const int wave = tid >> 6;
    const int wm = (wave >> 1) << 6;
    const int wn = (wave & 1) << 6;
    const int nk = K >> 5;

    // staging: thread tid -> tile row tid>>2 (0..63), 16-B segment tid&3
    const int srow = tid >> 2;
    const int sseg = (tid & 3) << 4;
    const char* gA0 = (const char*)(A + (long)(m0 + srow) * K) + sseg;        // rows 0-63
    const char* gA1 = (const char*)(A + (long)(m0 + 64 + srow) * K) + sseg;   // rows 64-127
    const char* gB0 = (const char*)(Bw + (long)(n0 + srow) * K) + sseg;
    const char* gB1 = (const char*)(Bw + (long)(n0 + 64 + srow) * K) + sseg;
    const int lofs = wave * 1024;

    f32x4 acc[4][4] = {};

    // prologue: stage tile 0 into buffer 0
    gload16(gA0, (char*)As[0] + lofs);
    gload16(gA1, (char*)As[0] + 4096 + lofs);
    gload16(gB0, (char*)Bs[0] + lofs);
    gload16(gB1, (char*)Bs[0] + 4096 + lofs);
    __syncthreads();                     // implicit vmcnt(0) drain: tile 0 ready

    int cur = 0;
    for (int kt = 0; kt < nk; kt++) {
        if (kt + 1 < nk) {               // stage NEXT tile (latency hides under MFMA)
            gload16(gA0 + (kt + 1) * 64, (char*)As[cur ^ 1] + lofs);
            gload16(gA1 + (kt + 1) * 64, (char*)As[cur ^ 1] + 4096 + lofs);
            gload16(gB0 + (kt + 1) * 64, (char*)Bs[cur ^ 1] + lofs);
            gload16(gB1 + (kt + 1) * 64, (char*)Bs[cur ^ 1] + 4096 + lofs);
        }
        bf16x8 af[4], bfr[4];
        #pragma unroll
        for (int mi = 0; mi < 4; mi++)
            af[mi] = *(const bf16x8*)((const char*)As[cur] +
                        (wm + mi * 16 + (lane & 15)) * 64 + ((lane >> 4) << 4));
        #pragma unroll
        for (int ni = 0; ni < 4; ni++)
            bfr[ni] = *(const bf16x8*)((const char*)Bs[cur] +
                        (wn + ni * 16 + (lane & 15)) * 64 + ((lane >> 4) << 4));
        #pragma unroll
        for (int mi = 0; mi < 4; mi++)
            #pragma unroll
            for (int ni = 0; ni < 4; ni++)
                acc[mi][ni] = __builtin_amdgcn_mfma_f32_16x16x32_bf16(
                                  af[mi], bfr[ni], acc[mi][ni], 0, 0, 0);
        __syncthreads();                 // drains vmcnt (next tile ready) + syncs reads
        cur ^= 1;
    }
    // epilogue: D col = lane&15, row = (lane>>4)*4 + r  (m89-verified layout)
    #pragma unroll
    for (int ni = 0; ni < 4; ni++) {
        const int col = n0 + wn + ni * 16 + (lane & 15);
        const float bv = bias[col];
        #pragma unroll
        for (int mi = 0; mi < 4; mi++) {
            const int row = m0 + wm + mi * 16 + ((lane >> 4) << 2);
            #pragma unroll
            for (int r = 0; r < 4; r++)
                Out[(long)(row + r) * N + col] = f2bf(acc[mi][ni][r] + bv);
        }
    }
}

// ---------------------------------------------------------------------------
// gru_scan: 256 blocks (1 batch each), 512 threads (8 waves, 2/SIMD).
// Pure-VALU int8 GEMV via v_dot4_i32_i8 (R7/R8 structure, unchanged).
// ---------------------------------------------------------------------------
__global__ __launch_bounds__(512, 2)
__attribute__((amdgpu_waves_per_eu(2, 2)))
void gru_scan(const unsigned short* __restrict__ xg,   // [51200][768] bf16 (incl biasC)
              const float* __restrict__ Whh,            // [768][256] fp32
              const float* __restrict__ bhh,            // [768]
              const int* __restrict__ lengths,          // [256]
              unsigned short* __restrict__ hout) {      // [51200][256] bf16 (masked)
    __shared__ __align__(16) unsigned char h8[2][256];  // int8 h double buffer
    const int tid = threadIdx.x;
    const int lane = tid & 63;
    const int wave = tid >> 6;               // 0..7
    const int b = blockIdx.x;
    const int col = wave * 32 + (lane & 31); // this thread's h-col
    const int kh = lane >> 5;                // K-half 0/1

    int W[3][32];
    #pragma unroll
    for (int g = 0; g < 3; g++) {
        const float* wr = Whh + (long)(g * 256 + col) * NH + kh * 128;
        #pragma unroll
        for (int d = 0; d < 32; d++) {
            const float4 f = *(const float4*)(wr + d * 4);
            unsigned pack = 0;
            #pragma unroll
            for (int j = 0; j < 4; j++) {
                const float fv = j == 0 ? f.x : j == 1 ? f.y : j == 2 ? f.z : f.w;
                int wq = (int)rintf(fv * 400.0f);
                wq = wq > 127 ? 127 : (wq < -127 ? -127 : wq);
                pack |= ((unsigned)(wq & 0xff)) << (8 * j);
            }
            W[g][d] = (int)pack;
        }
    }
    const float bhn = bhh[512 + col];        // n-gate b_hh (r,z folded into xg)
    const int len = lengths[b];
    if (tid < 128) ((unsigned*)h8)[tid] = 0u;   // zero both h buffers (512 B)

    const unsigned short* xrow = xg + (long)b * NT * G3H;
    unsigned short xv0 = xrow[col], xv1 = xrow[256 + col], xv2 = xrow[512 + col];
    float hp = 0.0f;
    const float ISC = 1.0f / (400.0f * 127.0f);
    const bool wlo = (lane < 32);

    asm volatile("s_waitcnt lgkmcnt(0)" ::: "memory");
    __builtin_amdgcn_sched_barrier(0);
    __builtin_amdgcn_s_barrier();
    __builtin_amdgcn_sched_barrier(0);

    for (int t = 0; t < NT; t++) {
        const unsigned char* hb = h8[(t + 1) & 1] + kh * 128;
        int p0a = 0, p0b = 0, p1a = 0, p1b = 0, p2a = 0, p2b = 0;
        #pragma unroll
        for (int r = 0; r < 8; r++) {
            const i32x4 hv = *(const i32x4*)(hb + r * 16);
            p0a = SDOT4(hv[0], W[0][r * 4 + 0], p0a);
            p1a = SDOT4(hv[0], W[1][r * 4 + 0], p1a);
            p2a = SDOT4(hv[0], W[2][r * 4 + 0], p2a);
            p0b = SDOT4(hv[1], W[0][r * 4 + 1], p0b);
            p1b = SDOT4(hv[1], W[1][r * 4 + 1], p1b);
            p2b = SDOT4(hv[1], W[2][r * 4 + 1], p2b);
            p0a = SDOT4(hv[2], W[0][r * 4 + 2], p0a);
            p1a = SDOT4(hv[2], W[1][r * 4 + 2], p1a);
            p2a = SDOT4(hv[2], W[2][r * 4 + 2], p2a);
            p0b = SDOT4(hv[3], W[0][r * 4 + 3], p0b);
            p1b = SDOT4(hv[3], W[1][r * 4 + 3], p1b);
            p2b = SDOT4(hv[3], W[2][r * 4 + 3], p2b);
        }
        int p0 = p0a + p0b, p1 = p1a + p1b, p2 = p2a + p2b;
        p0 += __shfl_xor(p0, 32);            // combine K-halves
        p1 += __shfl_xor(p1, 32);
        p2 += __shfl_xor(p2, 32);
        const float r = sigm(bf2f(xv0) + (float)p0 * ISC);
        const float z = sigm(bf2f(xv1) + (float)p1 * ISC);
        const float n = tanh_fast(bf2f(xv2) + r * ((float)p2 * ISC + bhn));
        hp = (1.0f - z) * n + z * hp;
        if (wlo) {
            h8[t & 1][col] = (unsigned char)((int)rintf(hp * 127.0f) & 0xff);
            hout[((long)b * NT + t) * NH + col] = (t < len) ? f2bf(hp) : (unsigned short)0;
        }
        if (t + 1 < NT) {
            const unsigned short* xn = xrow + (long)(t + 1) * G3H;
            xv0 = xn[col]; xv1 = xn[256 + col]; xv2 = xn[512 + col];
        }
        asm volatile("s_waitcnt lgkmcnt(0)" ::: "memory");
        __builtin_amdgcn_sched_barrier(0);
        __builtin_amdgcn_s_barrier();
        __builtin_amdgcn_sched_barrier(0);
    }
}

// ---------------------------------------------------------------------------
// prep2: fwe fp32 -> bf16, word_mask (sum|row| != 0), dvec[row] = fwe_row·b_out.
// One wave per row.
// ---------------------------------------------------------------------------
__global__ void prep2(const float* __restrict__ fwe, const float* __restrict__ bout,
                      unsigned short* __restrict__ fwebf,
                      unsigned char* __restrict__ wmask, float* __restrict__ dvec) {
    const int row = (int)((blockIdx.x * blockDim.x + threadIdx.x) >> 6);
    const int lane = threadIdx.x & 63;
    if (row >= MROWS) return;
    const float* s = fwe + (long)row * NE;
    unsigned short* d = fwebf + (long)row * NE;
    float asum = 0.0f, vdot = 0.0f;
    #pragma unroll
    for (int i = 0; i < 12; i++) {
        const float v = s[lane + i * 64];
        asum += fabsf(v);
        vdot += v * bout[lane + i * 64];
        d[lane + i * 64] = f2bf(v);
    }
    #pragma unroll
    for (int off = 32; off >= 1; off >>= 1) {
        asum += __shfl_xor(asum, off);
        vdot += __shfl_xor(vdot, off);
    }
    if (lane == 0) {
        wmask[row] = (asum != 0.0f) ? 1 : 0;
        dvec[row] = vdot;
    }
}

// ---------------------------------------------------------------------------
// logits_dur: wave per (b,t) row. The saccade window keeps only |w-fix|<=8
// (<=17 of 200 cols) -> compute only those dots (K=256): 4 w-slots x 16-lane
// K-split per pass, shfl-reduce; assemble the 200-wide row with -1e9 default
// and store float4-coalesced. dur = dot(h, W_dur) fused (same h slice).
// ---------------------------------------------------------------------------
__global__ __launch_bounds__(256)
void logits_dur(const unsigned short* __restrict__ Hrow,   // hout [51200][256]
                const unsigned short* __restrict__ G,      // [51200][256]
                const int* __restrict__ fix_seq,           // [51200]
                const unsigned char* __restrict__ wmask,   // [51200]
                const float* __restrict__ dvec,            // [51200]
                const float* __restrict__ Wdur, const float* __restrict__ bdur,
                float* __restrict__ out) {
    __shared__ float dots[4][20];
    const int wv = threadIdx.x >> 6;
    const int gwave = (int)blockIdx.x * 4 + wv;            // 0..51199 = b*200+t
    const int lane = threadIdx.x & 63;
    const int l16 = lane & 15;
    const int grp = lane >> 4;                              // 0..3
    const int b = gwave / NT;

    // h slice: lane's 16 k-elems [l16*16, +16), as fp32
    const unsigned short* hp = Hrow + (long)gwave * NH + l16 * 16;
    const bf16x8 h0 = *(const bf16x8*)hp;
    const bf16x8 h1 = *(const bf16x8*)(hp + 8);
    float hf[16];
    #pragma unroll
    for (int j = 0; j < 8; j++) { hf[j] = bf2f((unsigned short)h0[j]);
                                  hf[8 + j] = bf2f((unsigned short)h1[j]); }

    const int fix = fix_seq[gwave];
    const int wbase = fix - 8;

    if (fix != 0) {
        #pragma unroll
        for (int it = 0; it < 5; it++) {
            const int wi = it * 4 + grp;                    // 0..19 (17..19 unused)
            int w = wbase + wi;
            w = w < 0 ? 0 : (w > NW - 1 ? NW - 1 : w);      // clamp for safe load
            const unsigned short* gp = G + ((long)b * NW + w) * NH + l16 * 16;
            const bf16x8 g0 = *(const bf16x8*)gp;
            const bf16x8 g1 = *(const bf16x8*)(gp + 8);
            float p = 0.0f;
            #pragma unroll
            for (int j = 0; j < 8; j++) {
                p += hf[j] * bf2f((unsigned short)g0[j]);
                p += hf[8 + j] * bf2f((unsigned short)g1[j]);
            }
            p += __shfl_xor(p, 1); p += __shfl_xor(p, 2);
            p += __shfl_xor(p, 4); p += __shfl_xor(p, 8);
            if (l16 == 0 && wi < 17) dots[wv][wi] = p;
        }
    }
    // dur: all lanes (4x redundant), 16-lane reduce
    float pd = 0.0f;
    #pragma unroll
    for (int j = 0; j < 16; j++) pd += hf[j] * Wdur[l16 * 16 + j];
    pd += __shfl_xor(pd, 1); pd += __shfl_xor(pd, 2);
    pd += __shfl_xor(pd, 4); pd += __shfl_xor(pd, 8);
    if (lane == 0) out[(long)NB * NT * NW + gwave] = pd + bdur[0];

    __syncthreads();                                        // dots visible (lgkm drain)

    if (lane < 50) {
        float4 o;
        #pragma unroll
        for (int c = 0; c < 4; c++) {
            const int w = lane * 4 + c;
            const int wi = w - wbase;
            const int wic = wi < 0 ? 0 : (wi > 16 ? 16 : wi);
            const bool ok = (fix != 0) && ((unsigned)wi < 17u) && (wmask[b * NW + w] != 0);
            const float val = dots[wv][wic] + dvec[b * NW + w];
            ((float*)&o)[c] = ok ? val : -1e9f;
        }
        *(float4*)(out + (long)gwave * NW + lane * 4) = o;
    }
}

// ---------------------------------------------------------------------------
extern "C" void kernel_launch(void* const* d_in, const int* in_sizes, int n_in,
                              void* d_out, int out_size, void* d_ws, size_t ws_size,
                              hipStream_t stream) {
    (void)in_sizes; (void)n_in; (void)out_size; (void)ws_size;
    const float* inputs  = (const float*)d_in[0];
    const int*   fix_seq = (const int*)d_in[1];
    const float* fwe     = (const float*)d_in[2];
    const int*   lengths = (const int*)d_in[3];
    const float* emb     = (const float*)d_in[5];
    const float* Wih     = (const float*)d_in[6];
    const float* bih     = (const float*)d_in[7];
    const float* Whh     = (const float*)d_in[8];
    const float* bhh     = (const float*)d_in[9];
    const float* Wout    = (const float*)d_in[10];
    const float* bout    = (const float*)d_in[11];
    const float* Wdur    = (const float*)d_in[12];
    const float* bdur    = (const float*)d_in[13];
    float* out = (float*)d_out;

    char* ws = (char*)d_ws;
    // region layout (bytes, all 256-aligned):
    //   R0 [0, 81,920,000)            A_bf16 [51200][800]  -> fwebf after gemm1
    //   R1 [81,920,000, +78,643,200)  xg_bf16 [51200][768] -> G [51200][256] after gru
    //   R2 [160,563,200, +26,214,400) hout_bf16 [51200][256]
    //   [186,777,600, +1,228,800)     W_ih bf16
    //   [188,006,400, +393,216)       W_outT bf16 [256][768]
    //   [188,399,616, +51,200)        word_mask u8
    //   [188,450,816, +3,072)         biasC f32 [768]
    //   [188,453,888, +204,800)       dvec f32 [51200]
    //   [188,658,688, +1,024)         bias0 f32 [256]
    unsigned short* Abf     = (unsigned short*)(ws);
    unsigned short* xgbf    = (unsigned short*)(ws + 81920000);
    unsigned short* hout    = (unsigned short*)(ws + 160563200);
    unsigned short* Wihbf   = (unsigned short*)(ws + 186777600);
    unsigned short* WoutTbf = (unsigned short*)(ws + 188006400);
    unsigned char*  wmask   = (unsigned char*)(ws + 188399616);
    float*          biasC   = (float*)(ws + 188450816);
    float*          dvec    = (float*)(ws + 188453888);
    float*          bias0   = (float*)(ws + 188658688);
    unsigned short* fwebf   = Abf;    // R0: A dead after gemm1
    unsigned short* Gbf     = xgbf;   // R1: xg dead after gru

    prep1<<<2048, 256, 0, stream>>>(inputs, fix_seq, emb, Wih, Wout, bih, bhh,
                                    Abf, Wihbf, WoutTbf, biasC, bias0);
    gemm_bt128<<<400 * 6, 256, 0, stream>>>(Abf, Wihbf, biasC, xgbf, MROWS, G3H, KIN);
    prep2<<<12800, 256, 0, stream>>>(fwe, bout, fwebf, wmask, dvec);
    gru_scan<<<256, 512, 0, stream>>>(xgbf, Whh, bhh, lengths, hout);
    gemm_bt128<<<400 * 2, 256, 0, stream>>>(fwebf, WoutTbf, bias0, Gbf, MROWS, NH, NE);
    logits_dur<<<12800, 256, 0, stream>>>(hout, Gbf, fix_seq, wmask, dvec, Wdur, bdur, out);
}